// Round 1
// baseline (2528.411 us; speedup 1.0000x reference)
//
#include <hip/hip_runtime.h>
#include <math.h>

#define D_FEAT 12544
#define NE 8
#define NC 1000

// ---------------- K1: conv1(1->32,3x3,VALID)+ReLU+maxpool2 -> h1[128,31,31,32]
__global__ __launch_bounds__(256) void k1_conv1(
    const float* __restrict__ x, const float* __restrict__ w,
    const float* __restrict__ bias, float* __restrict__ h1)
{
    int co  = threadIdx.x & 31;
    int pxi = threadIdx.x >> 5;          // 0..7
    int blk = blockIdx.x;
    int pxg = blk & 3;
    int py  = (blk >> 2) % 31;
    int b   = blk / (31 * 4);
    int px  = pxg * 8 + pxi;
    if (px >= 31) return;

    float wr[9];
#pragma unroll
    for (int t = 0; t < 9; ++t) wr[t] = w[t * 32 + co];
    float bb = bias[co];

    float in[4][4];
    const float* xb = x + ((size_t)(b * 64 + 2 * py) * 64 + 2 * px);
#pragma unroll
    for (int r = 0; r < 4; ++r)
#pragma unroll
        for (int c = 0; c < 4; ++c)
            in[r][c] = xb[r * 64 + c];

    float a00 = 0.f, a01 = 0.f, a10 = 0.f, a11 = 0.f;
#pragma unroll
    for (int ky = 0; ky < 3; ++ky)
#pragma unroll
        for (int kx = 0; kx < 3; ++kx) {
            float wv = wr[ky * 3 + kx];
            a00 = fmaf(in[ky][kx],     wv, a00);
            a01 = fmaf(in[ky][kx + 1], wv, a01);
            a10 = fmaf(in[ky + 1][kx], wv, a10);
            a11 = fmaf(in[ky + 1][kx + 1], wv, a11);
        }
    a00 = fmaxf(a00 + bb, 0.f);
    a01 = fmaxf(a01 + bb, 0.f);
    a10 = fmaxf(a10 + bb, 0.f);
    a11 = fmaxf(a11 + bb, 0.f);
    float v = fmaxf(fmaxf(a00, a01), fmaxf(a10, a11));
    h1[((size_t)(b * 31 + py) * 31 + px) * 32 + co] = v;
}

// ---------------- K2: conv2(32->64,3x3,VALID)+ReLU+maxpool2 -> h[128,14,14,64]
// block: 448 thr = 32 co-local x 14 px; grid = 128 b x 14 py x 2 co-halves
__global__ __launch_bounds__(448) void k2_conv2(
    const float* __restrict__ h1, const float* __restrict__ w2,
    const float* __restrict__ b2, float* __restrict__ h)
{
    __shared__ float wl[9 * 32 * 32];    // [tap][ci][co_local] 36864 B

    int co  = threadIdx.x & 31;
    int px  = threadIdx.x >> 5;          // 0..13
    int blk = blockIdx.x;
    int cob = blk & 1;
    int py  = (blk >> 1) % 14;
    int b   = blk / 28;

    for (int i = threadIdx.x; i < 9 * 32 * 32; i += 448) {
        int tapci = i >> 5;
        int col   = i & 31;
        wl[i] = w2[tapci * 64 + cob * 32 + col];
    }
    __syncthreads();

    float acc00 = 0.f, acc01 = 0.f, acc10 = 0.f, acc11 = 0.f;
    const float* base = h1 + ((size_t)(b * 31 + 2 * py) * 31 + 2 * px) * 32;

    for (int q = 0; q < 8; ++q) {
        float4 in4[4][4];
#pragma unroll
        for (int r = 0; r < 4; ++r)
#pragma unroll
            for (int c = 0; c < 4; ++c)
                in4[r][c] = *(const float4*)(base + (r * 31 + c) * 32 + q * 4);

#pragma unroll
        for (int ky = 0; ky < 3; ++ky)
#pragma unroll
            for (int kx = 0; kx < 3; ++kx) {
                int tap = ky * 3 + kx;
                const float* wp = &wl[(tap * 32 + q * 4) * 32 + co];
                float w0 = wp[0];
                float w1 = wp[32];
                float w2v = wp[64];
                float w3 = wp[96];
                acc00 = fmaf(in4[ky][kx].x, w0, acc00);
                acc00 = fmaf(in4[ky][kx].y, w1, acc00);
                acc00 = fmaf(in4[ky][kx].z, w2v, acc00);
                acc00 = fmaf(in4[ky][kx].w, w3, acc00);
                acc01 = fmaf(in4[ky][kx + 1].x, w0, acc01);
                acc01 = fmaf(in4[ky][kx + 1].y, w1, acc01);
                acc01 = fmaf(in4[ky][kx + 1].z, w2v, acc01);
                acc01 = fmaf(in4[ky][kx + 1].w, w3, acc01);
                acc10 = fmaf(in4[ky + 1][kx].x, w0, acc10);
                acc10 = fmaf(in4[ky + 1][kx].y, w1, acc10);
                acc10 = fmaf(in4[ky + 1][kx].z, w2v, acc10);
                acc10 = fmaf(in4[ky + 1][kx].w, w3, acc10);
                acc11 = fmaf(in4[ky + 1][kx + 1].x, w0, acc11);
                acc11 = fmaf(in4[ky + 1][kx + 1].y, w1, acc11);
                acc11 = fmaf(in4[ky + 1][kx + 1].z, w2v, acc11);
                acc11 = fmaf(in4[ky + 1][kx + 1].w, w3, acc11);
            }
    }

    float bb = b2[cob * 32 + co];
    acc00 = fmaxf(acc00 + bb, 0.f);
    acc01 = fmaxf(acc01 + bb, 0.f);
    acc10 = fmaxf(acc10 + bb, 0.f);
    acc11 = fmaxf(acc11 + bb, 0.f);
    float v = fmaxf(fmaxf(acc00, acc01), fmaxf(acc10, acc11));
    // flatten d = (py*14+px)*64 + co_global
    h[(size_t)b * D_FEAT + (py * 14 + px) * 64 + cob * 32 + co] = v;
}

// ---------------- K3: gate logits + softmax + top2 + routing lists
__global__ __launch_bounds__(256) void k3_gate(
    const float* __restrict__ h, const float* __restrict__ gw,
    const float* __restrict__ gb, int* __restrict__ cnt,
    int* __restrict__ rowIdx, float* __restrict__ rowW)
{
    int b = blockIdx.x;
    int tid = threadIdx.x;
    float acc[8];
#pragma unroll
    for (int e = 0; e < 8; ++e) acc[e] = 0.f;

    const float* hb = h + (size_t)b * D_FEAT;
    for (int d = tid; d < D_FEAT; d += 256) {
        float hv = hb[d];
        float4 g0 = *(const float4*)(gw + (size_t)d * 8);
        float4 g1 = *(const float4*)(gw + (size_t)d * 8 + 4);
        acc[0] = fmaf(hv, g0.x, acc[0]);
        acc[1] = fmaf(hv, g0.y, acc[1]);
        acc[2] = fmaf(hv, g0.z, acc[2]);
        acc[3] = fmaf(hv, g0.w, acc[3]);
        acc[4] = fmaf(hv, g1.x, acc[4]);
        acc[5] = fmaf(hv, g1.y, acc[5]);
        acc[6] = fmaf(hv, g1.z, acc[6]);
        acc[7] = fmaf(hv, g1.w, acc[7]);
    }

#pragma unroll
    for (int e = 0; e < 8; ++e) {
        float v = acc[e];
        v += __shfl_down(v, 32, 64);
        v += __shfl_down(v, 16, 64);
        v += __shfl_down(v, 8, 64);
        v += __shfl_down(v, 4, 64);
        v += __shfl_down(v, 2, 64);
        v += __shfl_down(v, 1, 64);
        acc[e] = v;
    }

    __shared__ float sm[4][8];
    int wid = tid >> 6, ln = tid & 63;
    if (ln == 0) {
#pragma unroll
        for (int e = 0; e < 8; ++e) sm[wid][e] = acc[e];
    }
    __syncthreads();

    if (tid == 0) {
        float lg[8], p[8];
        float m = -1e30f;
#pragma unroll
        for (int e = 0; e < 8; ++e) {
            lg[e] = sm[0][e] + sm[1][e] + sm[2][e] + sm[3][e] + gb[e];
            m = fmaxf(m, lg[e]);
        }
        float s = 0.f;
#pragma unroll
        for (int e = 0; e < 8; ++e) { p[e] = expf(lg[e] - m); s += p[e]; }
        float inv = 1.f / s;
#pragma unroll
        for (int e = 0; e < 8; ++e) p[e] *= inv;

        int i0 = 0;
#pragma unroll
        for (int e = 1; e < 8; ++e) if (p[e] > p[i0]) i0 = e;
        int i1 = (i0 == 0) ? 1 : 0;
#pragma unroll
        for (int e = 0; e < 8; ++e) if (e != i0 && p[e] > p[i1]) i1 = e;

        int pos0 = atomicAdd(&cnt[i0], 1);
        rowIdx[i0 * 128 + pos0] = b;
        rowW[i0 * 128 + pos0] = p[i0];
        int pos1 = atomicAdd(&cnt[i1], 1);
        rowIdx[i1 * 128 + pos1] = b;
        rowW[i1 * 128 + pos1] = p[i1];
    }
}

// ---------------- K4: grouped expert GEMM, weight slab read exactly once
// grid = 8 experts x 32 c-tiles(32 cols); block 256 = 32 cols x 8 row-groups
__global__ __launch_bounds__(256) void k4_expert(
    const float* __restrict__ h, const float* __restrict__ ew,
    const float* __restrict__ eb, const int* __restrict__ cnt,
    const int* __restrict__ rowIdx, const float* __restrict__ rowW,
    float* __restrict__ comb)
{
    int e  = blockIdx.x >> 5;
    int ct = blockIdx.x & 31;
    int c  = ct * 32 + (threadIdx.x & 31);
    int rg = threadIdx.x >> 5;           // 0..7
    int n  = cnt[e];
    if (n == 0 || c >= NC) return;

    const float* W = ew + (size_t)e * D_FEAT * NC + c;

    float acc[16];
    const float* hp[16];
    bool val[16];
#pragma unroll
    for (int i = 0; i < 16; ++i) {
        int r = rg + i * 8;
        val[i] = (r < n);
        int row = val[i] ? rowIdx[e * 128 + r] : 0;
        hp[i] = h + (size_t)row * D_FEAT;
        acc[i] = 0.f;
    }

    for (int d0 = 0; d0 < D_FEAT; d0 += 16) {
        float wv[16];
#pragma unroll
        for (int j = 0; j < 16; ++j)
            wv[j] = W[(size_t)(d0 + j) * NC];
#pragma unroll
        for (int i = 0; i < 16; ++i) {
            if (val[i]) {
                float4 p0 = *(const float4*)(hp[i] + d0);
                float4 p1 = *(const float4*)(hp[i] + d0 + 4);
                float4 p2 = *(const float4*)(hp[i] + d0 + 8);
                float4 p3 = *(const float4*)(hp[i] + d0 + 12);
                float a = acc[i];
                a = fmaf(p0.x, wv[0], a);
                a = fmaf(p0.y, wv[1], a);
                a = fmaf(p0.z, wv[2], a);
                a = fmaf(p0.w, wv[3], a);
                a = fmaf(p1.x, wv[4], a);
                a = fmaf(p1.y, wv[5], a);
                a = fmaf(p1.z, wv[6], a);
                a = fmaf(p1.w, wv[7], a);
                a = fmaf(p2.x, wv[8], a);
                a = fmaf(p2.y, wv[9], a);
                a = fmaf(p2.z, wv[10], a);
                a = fmaf(p2.w, wv[11], a);
                a = fmaf(p3.x, wv[12], a);
                a = fmaf(p3.y, wv[13], a);
                a = fmaf(p3.z, wv[14], a);
                a = fmaf(p3.w, wv[15], a);
                acc[i] = a;
            }
        }
    }

    float bias = eb[e * NC + c];
#pragma unroll
    for (int i = 0; i < 16; ++i) {
        if (val[i]) {
            int r = rg + i * 8;
            float wgt = rowW[e * 128 + r];
            int bi = rowIdx[e * 128 + r];
            atomicAdd(&comb[bi * NC + c], wgt * (acc[i] + bias));
        }
    }
}

// ---------------- K5: row softmax over 1000 classes
__global__ __launch_bounds__(256) void k5_softmax(
    const float* __restrict__ comb, float* __restrict__ out)
{
    int b = blockIdx.x;
    int tid = threadIdx.x;
    __shared__ float red[4];

    float v[4];
    bool val[4];
#pragma unroll
    for (int i = 0; i < 4; ++i) {
        int c = tid + i * 256;
        val[i] = (c < NC);
        v[i] = val[i] ? comb[b * NC + c] : -1e30f;
    }

    float m = fmaxf(fmaxf(v[0], v[1]), fmaxf(v[2], v[3]));
#pragma unroll
    for (int off = 32; off >= 1; off >>= 1)
        m = fmaxf(m, __shfl_xor(m, off, 64));
    int wid = tid >> 6, ln = tid & 63;
    if (ln == 0) red[wid] = m;
    __syncthreads();
    m = fmaxf(fmaxf(red[0], red[1]), fmaxf(red[2], red[3]));
    __syncthreads();

    float ex[4];
    float s = 0.f;
#pragma unroll
    for (int i = 0; i < 4; ++i) {
        ex[i] = val[i] ? expf(v[i] - m) : 0.f;
        s += ex[i];
    }
#pragma unroll
    for (int off = 32; off >= 1; off >>= 1)
        s += __shfl_xor(s, off, 64);
    if (ln == 0) red[wid] = s;
    __syncthreads();
    s = red[0] + red[1] + red[2] + red[3];
    float inv = 1.f / s;

#pragma unroll
    for (int i = 0; i < 4; ++i) {
        int c = tid + i * 256;
        if (val[i]) out[b * NC + c] = ex[i] * inv;
    }
}

extern "C" void kernel_launch(void* const* d_in, const int* in_sizes, int n_in,
                              void* d_out, int out_size, void* d_ws, size_t ws_size,
                              hipStream_t stream) {
    const float* x   = (const float*)d_in[0];
    const float* c1w = (const float*)d_in[1];
    const float* c1b = (const float*)d_in[2];
    const float* c2w = (const float*)d_in[3];
    const float* c2b = (const float*)d_in[4];
    const float* gw  = (const float*)d_in[5];
    const float* gb  = (const float*)d_in[6];
    const float* ew  = (const float*)d_in[7];
    const float* eb  = (const float*)d_in[8];
    float* out = (float*)d_out;

    char* ws = (char*)d_ws;
    float* h1     = (float*)(ws + 0);           // 15,745,024 B
    float* h      = (float*)(ws + 15745024);    //  6,422,528 B
    float* comb   = (float*)(ws + 22167552);    //    512,000 B
    int*   cnt    = (int*)  (ws + 22679552);    //         32 B
    int*   rowIdx = (int*)  (ws + 22679584);    //      4,096 B
    float* rowW   = (float*)(ws + 22683680);    //      4,096 B

    // zero combined accumulator + routing counts (contiguous region)
    hipMemsetAsync(ws + 22167552, 0, 512032, stream);

    k1_conv1<<<128 * 31 * 4, 256, 0, stream>>>(x, c1w, c1b, h1);
    k2_conv2<<<128 * 14 * 2, 448, 0, stream>>>(h1, c2w, c2b, h);
    k3_gate<<<128, 256, 0, stream>>>(h, gw, gb, cnt, rowIdx, rowW);
    k4_expert<<<256, 256, 0, stream>>>(h, ew, eb, cnt, rowIdx, rowW, comb);
    k5_softmax<<<128, 256, 0, stream>>>(comb, out);
}

// Round 2
// 420.757 us; speedup vs baseline: 6.0092x; 6.0092x over previous
//
#include <hip/hip_runtime.h>
#include <math.h>

#define D_FEAT 12544
#define NC 1000
#define R4 32          // rows per k4 block
#define ND 32          // D chunks
#define DCHUNK 392     // D_FEAT / ND
#define DSUB 196       // LDS sub-chunk (2 per chunk)
#define NSUB 2

// ---------------- K1: conv1(1->32,3x3,VALID)+ReLU+maxpool2 -> h1[128,31,31,32]
__global__ __launch_bounds__(256) void k1_conv1(
    const float* __restrict__ x, const float* __restrict__ w,
    const float* __restrict__ bias, float* __restrict__ h1)
{
    int co  = threadIdx.x & 31;
    int pxi = threadIdx.x >> 5;          // 0..7
    int blk = blockIdx.x;
    int pxg = blk & 3;
    int py  = (blk >> 2) % 31;
    int b   = blk / (31 * 4);
    int px  = pxg * 8 + pxi;
    if (px >= 31) return;

    float wr[9];
#pragma unroll
    for (int t = 0; t < 9; ++t) wr[t] = w[t * 32 + co];
    float bb = bias[co];

    float in[4][4];
    const float* xb = x + ((size_t)(b * 64 + 2 * py) * 64 + 2 * px);
#pragma unroll
    for (int r = 0; r < 4; ++r)
#pragma unroll
        for (int c = 0; c < 4; ++c)
            in[r][c] = xb[r * 64 + c];

    float a00 = 0.f, a01 = 0.f, a10 = 0.f, a11 = 0.f;
#pragma unroll
    for (int ky = 0; ky < 3; ++ky)
#pragma unroll
        for (int kx = 0; kx < 3; ++kx) {
            float wv = wr[ky * 3 + kx];
            a00 = fmaf(in[ky][kx],     wv, a00);
            a01 = fmaf(in[ky][kx + 1], wv, a01);
            a10 = fmaf(in[ky + 1][kx], wv, a10);
            a11 = fmaf(in[ky + 1][kx + 1], wv, a11);
        }
    a00 = fmaxf(a00 + bb, 0.f);
    a01 = fmaxf(a01 + bb, 0.f);
    a10 = fmaxf(a10 + bb, 0.f);
    a11 = fmaxf(a11 + bb, 0.f);
    float v = fmaxf(fmaxf(a00, a01), fmaxf(a10, a11));
    h1[((size_t)(b * 31 + py) * 31 + px) * 32 + co] = v;
}

// ---------------- K2: conv2(32->64,3x3,VALID)+ReLU+maxpool2 -> h[128,14,14,64]
__global__ __launch_bounds__(448) void k2_conv2(
    const float* __restrict__ h1, const float* __restrict__ w2,
    const float* __restrict__ b2, float* __restrict__ h)
{
    __shared__ float wl[9 * 32 * 32];    // [tap][ci][co_local] 36864 B

    int co  = threadIdx.x & 31;
    int px  = threadIdx.x >> 5;          // 0..13
    int blk = blockIdx.x;
    int cob = blk & 1;
    int py  = (blk >> 1) % 14;
    int b   = blk / 28;

    for (int i = threadIdx.x; i < 9 * 32 * 32; i += 448) {
        int tapci = i >> 5;
        int col   = i & 31;
        wl[i] = w2[tapci * 64 + cob * 32 + col];
    }
    __syncthreads();

    float acc00 = 0.f, acc01 = 0.f, acc10 = 0.f, acc11 = 0.f;
    const float* base = h1 + ((size_t)(b * 31 + 2 * py) * 31 + 2 * px) * 32;

    for (int q = 0; q < 8; ++q) {
        float4 in4[4][4];
#pragma unroll
        for (int r = 0; r < 4; ++r)
#pragma unroll
            for (int c = 0; c < 4; ++c)
                in4[r][c] = *(const float4*)(base + (r * 31 + c) * 32 + q * 4);

#pragma unroll
        for (int ky = 0; ky < 3; ++ky)
#pragma unroll
            for (int kx = 0; kx < 3; ++kx) {
                int tap = ky * 3 + kx;
                const float* wp = &wl[(tap * 32 + q * 4) * 32 + co];
                float w0 = wp[0];
                float w1 = wp[32];
                float w2v = wp[64];
                float w3 = wp[96];
                acc00 = fmaf(in4[ky][kx].x, w0, acc00);
                acc00 = fmaf(in4[ky][kx].y, w1, acc00);
                acc00 = fmaf(in4[ky][kx].z, w2v, acc00);
                acc00 = fmaf(in4[ky][kx].w, w3, acc00);
                acc01 = fmaf(in4[ky][kx + 1].x, w0, acc01);
                acc01 = fmaf(in4[ky][kx + 1].y, w1, acc01);
                acc01 = fmaf(in4[ky][kx + 1].z, w2v, acc01);
                acc01 = fmaf(in4[ky][kx + 1].w, w3, acc01);
                acc10 = fmaf(in4[ky + 1][kx].x, w0, acc10);
                acc10 = fmaf(in4[ky + 1][kx].y, w1, acc10);
                acc10 = fmaf(in4[ky + 1][kx].z, w2v, acc10);
                acc10 = fmaf(in4[ky + 1][kx].w, w3, acc10);
                acc11 = fmaf(in4[ky + 1][kx + 1].x, w0, acc11);
                acc11 = fmaf(in4[ky + 1][kx + 1].y, w1, acc11);
                acc11 = fmaf(in4[ky + 1][kx + 1].z, w2v, acc11);
                acc11 = fmaf(in4[ky + 1][kx + 1].w, w3, acc11);
            }
    }

    float bb = b2[cob * 32 + co];
    acc00 = fmaxf(acc00 + bb, 0.f);
    acc01 = fmaxf(acc01 + bb, 0.f);
    acc10 = fmaxf(acc10 + bb, 0.f);
    acc11 = fmaxf(acc11 + bb, 0.f);
    float v = fmaxf(fmaxf(acc00, acc01), fmaxf(acc10, acc11));
    h[(size_t)b * D_FEAT + (py * 14 + px) * 64 + cob * 32 + co] = v;
}

// ---------------- K3: gate logits + softmax + top2 + routing lists
__global__ __launch_bounds__(256) void k3_gate(
    const float* __restrict__ h, const float* __restrict__ gw,
    const float* __restrict__ gb, int* __restrict__ cnt,
    int* __restrict__ rowIdx, float* __restrict__ rowW,
    int* __restrict__ top2e, float* __restrict__ top2w)
{
    int b = blockIdx.x;
    int tid = threadIdx.x;
    float acc[8];
#pragma unroll
    for (int e = 0; e < 8; ++e) acc[e] = 0.f;

    const float* hb = h + (size_t)b * D_FEAT;
    for (int d = tid; d < D_FEAT; d += 256) {
        float hv = hb[d];
        float4 g0 = *(const float4*)(gw + (size_t)d * 8);
        float4 g1 = *(const float4*)(gw + (size_t)d * 8 + 4);
        acc[0] = fmaf(hv, g0.x, acc[0]);
        acc[1] = fmaf(hv, g0.y, acc[1]);
        acc[2] = fmaf(hv, g0.z, acc[2]);
        acc[3] = fmaf(hv, g0.w, acc[3]);
        acc[4] = fmaf(hv, g1.x, acc[4]);
        acc[5] = fmaf(hv, g1.y, acc[5]);
        acc[6] = fmaf(hv, g1.z, acc[6]);
        acc[7] = fmaf(hv, g1.w, acc[7]);
    }

#pragma unroll
    for (int e = 0; e < 8; ++e) {
        float v = acc[e];
        v += __shfl_down(v, 32, 64);
        v += __shfl_down(v, 16, 64);
        v += __shfl_down(v, 8, 64);
        v += __shfl_down(v, 4, 64);
        v += __shfl_down(v, 2, 64);
        v += __shfl_down(v, 1, 64);
        acc[e] = v;
    }

    __shared__ float sm[4][8];
    int wid = tid >> 6, ln = tid & 63;
    if (ln == 0) {
#pragma unroll
        for (int e = 0; e < 8; ++e) sm[wid][e] = acc[e];
    }
    __syncthreads();

    if (tid == 0) {
        float lg[8], p[8];
        float m = -1e30f;
#pragma unroll
        for (int e = 0; e < 8; ++e) {
            lg[e] = sm[0][e] + sm[1][e] + sm[2][e] + sm[3][e] + gb[e];
            m = fmaxf(m, lg[e]);
        }
        float s = 0.f;
#pragma unroll
        for (int e = 0; e < 8; ++e) { p[e] = expf(lg[e] - m); s += p[e]; }
        float inv = 1.f / s;
#pragma unroll
        for (int e = 0; e < 8; ++e) p[e] *= inv;

        int i0 = 0;
#pragma unroll
        for (int e = 1; e < 8; ++e) if (p[e] > p[i0]) i0 = e;
        int i1 = (i0 == 0) ? 1 : 0;
#pragma unroll
        for (int e = 0; e < 8; ++e) if (e != i0 && p[e] > p[i1]) i1 = e;

        int pos0 = atomicAdd(&cnt[i0], 1);
        rowIdx[i0 * 128 + pos0] = b;
        rowW[i0 * 128 + pos0] = p[i0];
        int pos1 = atomicAdd(&cnt[i1], 1);
        rowIdx[i1 * 128 + pos1] = b;
        rowW[i1 * 128 + pos1] = p[i1];

        top2e[b * 2]     = i0;
        top2e[b * 2 + 1] = i1;
        top2w[b * 2]     = p[i0];
        top2w[b * 2 + 1] = p[i1];
    }
}

// ---------------- K4: grouped expert GEMM partials
// grid = 8 e x 4 row-chunks x 32 D-chunks; block 256 thr, 4 cols/thread
__global__ __launch_bounds__(256, 2) void k4_expert(
    const float* __restrict__ h, const float* __restrict__ ew,
    const int* __restrict__ cnt, const int* __restrict__ rowIdx,
    const float* __restrict__ rowW, float* __restrict__ comb)
{
    __shared__ float h_lds[R4 * DSUB];          // 25088 B
    __shared__ int   ridx_s[R4];
    __shared__ int   roff_s[R4];
    __shared__ float rwgt_s[R4];

    int tid = threadIdx.x;
    int bid = blockIdx.x;
    int nd = bid & 31;
    int rc = (bid >> 5) & 3;
    int e  = bid >> 7;

    int n = cnt[e];
    int rbase = rc * R4;
    if (rbase >= n) return;
    int nrows = n - rbase; if (nrows > R4) nrows = R4;

    if (tid < R4) {
        int valid = tid < nrows;
        int ri = valid ? rowIdx[e * 128 + rbase + tid] : 0;
        ridx_s[tid] = ri;
        roff_s[tid] = ri * D_FEAT;
        rwgt_s[tid] = valid ? rowW[e * 128 + rbase + tid] : 0.f;
    }
    __syncthreads();

    int c0 = tid * 4;
    bool act = (c0 < NC);                 // tid < 250
    const float* Wb = ew + (size_t)e * D_FEAT * NC + c0;
    int dbase = nd * DCHUNK;

    float4 acc[R4];
#pragma unroll
    for (int r = 0; r < R4; ++r) acc[r] = make_float4(0.f, 0.f, 0.f, 0.f);

    for (int s = 0; s < NSUB; ++s) {
        int dstart = dbase + s * DSUB;
        // stage h rows [nrows x DSUB] into LDS (zeros for invalid rows)
        for (int i = tid; i < R4 * (DSUB / 4); i += 256) {
            int r = i / (DSUB / 4);
            int q = i - r * (DSUB / 4);
            float4 v = make_float4(0.f, 0.f, 0.f, 0.f);
            if (r < nrows)
                v = *(const float4*)(h + roff_s[r] + dstart + q * 4);
            *(float4*)&h_lds[r * DSUB + q * 4] = v;
        }
        __syncthreads();

        if (act) {
            for (int st = 0; st < DSUB / 4; ++st) {
                const float* wp = Wb + (size_t)(dstart + st * 4) * NC;
                float4 w0 = *(const float4*)(wp);
                float4 w1 = *(const float4*)(wp + NC);
                float4 w2 = *(const float4*)(wp + 2 * NC);
                float4 w3 = *(const float4*)(wp + 3 * NC);
#pragma unroll
                for (int g = 0; g < 4; ++g) {
                    if (g * 8 < nrows) {
#pragma unroll
                        for (int rr = 0; rr < 8; ++rr) {
                            int r = g * 8 + rr;
                            float4 h4 = *(const float4*)&h_lds[r * DSUB + st * 4];
                            float4 a = acc[r];
                            a.x = fmaf(h4.x, w0.x, a.x);
                            a.x = fmaf(h4.y, w1.x, a.x);
                            a.x = fmaf(h4.z, w2.x, a.x);
                            a.x = fmaf(h4.w, w3.x, a.x);
                            a.y = fmaf(h4.x, w0.y, a.y);
                            a.y = fmaf(h4.y, w1.y, a.y);
                            a.y = fmaf(h4.z, w2.y, a.y);
                            a.y = fmaf(h4.w, w3.y, a.y);
                            a.z = fmaf(h4.x, w0.z, a.z);
                            a.z = fmaf(h4.y, w1.z, a.z);
                            a.z = fmaf(h4.z, w2.z, a.z);
                            a.z = fmaf(h4.w, w3.z, a.z);
                            a.w = fmaf(h4.x, w0.w, a.w);
                            a.w = fmaf(h4.y, w1.w, a.w);
                            a.w = fmaf(h4.z, w2.w, a.w);
                            a.w = fmaf(h4.w, w3.w, a.w);
                            acc[r] = a;
                        }
                    }
                }
            }
        }
        __syncthreads();
    }

    if (act) {
#pragma unroll
        for (int r = 0; r < R4; ++r) {
            if (r < nrows) {
                float wgt = rwgt_s[r];
                float* cp = comb + ridx_s[r] * NC + c0;
                atomicAdd(cp + 0, wgt * acc[r].x);
                atomicAdd(cp + 1, wgt * acc[r].y);
                atomicAdd(cp + 2, wgt * acc[r].z);
                atomicAdd(cp + 3, wgt * acc[r].w);
            }
        }
    }
}

// ---------------- K5: add weighted expert bias, row softmax over 1000 classes
__global__ __launch_bounds__(256) void k5_softmax(
    const float* __restrict__ comb, const float* __restrict__ eb,
    const int* __restrict__ top2e, const float* __restrict__ top2w,
    float* __restrict__ out)
{
    int b = blockIdx.x;
    int tid = threadIdx.x;
    __shared__ float red[4];

    int e0 = top2e[b * 2], e1 = top2e[b * 2 + 1];
    float tw0 = top2w[b * 2], tw1 = top2w[b * 2 + 1];
    const float* eb0 = eb + e0 * NC;
    const float* eb1 = eb + e1 * NC;

    float v[4];
    bool val[4];
#pragma unroll
    for (int i = 0; i < 4; ++i) {
        int c = tid + i * 256;
        val[i] = (c < NC);
        v[i] = val[i] ? (comb[b * NC + c] + tw0 * eb0[c] + tw1 * eb1[c]) : -1e30f;
    }

    float m = fmaxf(fmaxf(v[0], v[1]), fmaxf(v[2], v[3]));
#pragma unroll
    for (int off = 32; off >= 1; off >>= 1)
        m = fmaxf(m, __shfl_xor(m, off, 64));
    int wid = tid >> 6, ln = tid & 63;
    if (ln == 0) red[wid] = m;
    __syncthreads();
    m = fmaxf(fmaxf(red[0], red[1]), fmaxf(red[2], red[3]));
    __syncthreads();

    float ex[4];
    float s = 0.f;
#pragma unroll
    for (int i = 0; i < 4; ++i) {
        ex[i] = val[i] ? expf(v[i] - m) : 0.f;
        s += ex[i];
    }
#pragma unroll
    for (int off = 32; off >= 1; off >>= 1)
        s += __shfl_xor(s, off, 64);
    if (ln == 0) red[wid] = s;
    __syncthreads();
    s = red[0] + red[1] + red[2] + red[3];
    float inv = 1.f / s;

#pragma unroll
    for (int i = 0; i < 4; ++i) {
        int c = tid + i * 256;
        if (val[i]) out[b * NC + c] = ex[i] * inv;
    }
}

extern "C" void kernel_launch(void* const* d_in, const int* in_sizes, int n_in,
                              void* d_out, int out_size, void* d_ws, size_t ws_size,
                              hipStream_t stream) {
    const float* x   = (const float*)d_in[0];
    const float* c1w = (const float*)d_in[1];
    const float* c1b = (const float*)d_in[2];
    const float* c2w = (const float*)d_in[3];
    const float* c2b = (const float*)d_in[4];
    const float* gw  = (const float*)d_in[5];
    const float* gb  = (const float*)d_in[6];
    const float* ew  = (const float*)d_in[7];
    const float* eb  = (const float*)d_in[8];
    float* out = (float*)d_out;

    char* ws = (char*)d_ws;
    float* h1     = (float*)(ws + 0);           // 15,745,024 B
    float* h      = (float*)(ws + 15745024);    //  6,422,528 B
    float* comb   = (float*)(ws + 22167552);    //    512,000 B
    int*   cnt    = (int*)  (ws + 22679552);    //         32 B
    int*   rowIdx = (int*)  (ws + 22679584);    //      4,096 B
    float* rowW   = (float*)(ws + 22683680);    //      4,096 B
    int*   top2e  = (int*)  (ws + 22687776);    //      1,024 B
    float* top2w  = (float*)(ws + 22688800);    //      1,024 B

    // zero combined accumulator + routing counts (contiguous region)
    hipMemsetAsync(ws + 22167552, 0, 512032, stream);

    k1_conv1<<<128 * 31 * 4, 256, 0, stream>>>(x, c1w, c1b, h1);
    k2_conv2<<<128 * 14 * 2, 448, 0, stream>>>(h1, c2w, c2b, h);
    k3_gate<<<128, 256, 0, stream>>>(h, gw, gb, cnt, rowIdx, rowW, top2e, top2w);
    k4_expert<<<8 * 4 * 32, 256, 0, stream>>>(h, ew, cnt, rowIdx, rowW, comb);
    k5_softmax<<<128, 256, 0, stream>>>(comb, eb, top2e, top2w, out);
}